// Round 3
// baseline (205.684 us; speedup 1.0000x reference)
//
#include <hip/hip_runtime.h>

typedef __bf16 bf16;
typedef bf16 bf16x8 __attribute__((ext_vector_type(8)));
typedef float f32x4 __attribute__((ext_vector_type(4)));

#define PTS 16       // points per block
#define TPITCH 200   // bf16 elems per T row (192 + 8 pad) -> 400B row stride, 16B aligned

// LDS: T 48*200*2 = 19200 B + Y 4*16*48*4 = 12288 B = 31488 B -> 5 blocks/CU (20 waves/CU).
// Exactly ONE __syncthreads (T transpose). Y staging is wave-private: scatter + readback
// ordered by the wave's own lgkmcnt, no block barrier.

__global__ __launch_bounds__(256, 5)
void affine_linear_fused(const float* __restrict__ X, const float* __restrict__ J,
                         const float* __restrict__ A, const float* __restrict__ Bm,
                         const float* __restrict__ C, float* __restrict__ Y)
{
    __shared__ __attribute__((aligned(16))) bf16 T_lds[48 * TPITCH];
    __shared__ __attribute__((aligned(16))) float Y_lds[4][PTS * 48];  // [wave][p*48 + fl*3 + i]

    const int tid  = threadIdx.x;
    const int wave = tid >> 6;
    const int lane = tid & 63;
    const int l16  = lane & 15;
    const int lq   = lane >> 4;       // quad 0..3
    const long bn0 = (long)blockIdx.x * PTS;

    // ---- Issue all J/X loads (long-latency HBM) for this wave's 4 points first ----
    float j0[4], j1[4], j2[4], j3[4], j4[4], j5[4];
    float x0[4], x1[4], x2[4];
    #pragma unroll
    for (int q = 0; q < 4; ++q) {
        long bn = bn0 + wave * 4 + q;
        const float* Jc = J + (bn * 64 + lane) * 6;
        const float* Xc = X + (bn * 64 + lane) * 3;
        float2 ja = *(const float2*)(Jc + 0);
        float2 jb = *(const float2*)(Jc + 2);
        float2 jc = *(const float2*)(Jc + 4);
        j0[q] = ja.x; j1[q] = ja.y;
        j2[q] = jb.x; j3[q] = jb.y;
        j4[q] = jc.x; j5[q] = jc.y;
        x0[q] = Xc[0]; x1[q] = Xc[1]; x2[q] = Xc[2];
    }

    // ---- W fragments from global (L2/L3-hot after first blocks) ----
    // W[f, k]: f = wave*16+l16; k = kk*32 + lq*8 + j; segments kk<2:A, <4:Bm, else C
    const int f = wave * 16 + l16;
    bf16x8 wfrag[6];
    #pragma unroll
    for (int kk = 0; kk < 6; ++kk) {
        const float* src = (kk < 2) ? A : (kk < 4) ? Bm : C;
        const f32x4* p4 = (const f32x4*)(src + f * 64 + (kk & 1) * 32 + lq * 8);
        f32x4 lo = p4[0], hi = p4[1];
        bf16x8 w;
        w[0] = (bf16)lo[0]; w[1] = (bf16)lo[1]; w[2] = (bf16)lo[2]; w[3] = (bf16)lo[3];
        w[4] = (bf16)hi[0]; w[5] = (bf16)hi[1]; w[6] = (bf16)hi[2]; w[7] = (bf16)hi[3];
        wfrag[kk] = w;
    }

    // ---- Terms: wave w handles points 4w+q, lane = channel d ----
    #pragma unroll
    for (int q = 0; q < 4; ++q) {
        int p = wave * 4 + q;
        float a1x = j0[q], a2x = j1[q];
        float a1y = j2[q], a2y = j3[q];
        float a1z = j4[q], a2z = j5[q];
        float xx = x0[q], xy = x1[q], xz = x2[q];

        float n1   = sqrtf(a1x*a1x + a1y*a1y + a1z*a1z);
        float inv1 = 1.0f / fmaxf(n1, 1e-12f);
        float b1x = a1x*inv1, b1y = a1y*inv1, b1z = a1z*inv1;
        float dot = b1x*a2x + b1y*a2y + b1z*a2z;
        float ux = a2x - dot*b1x, uy = a2y - dot*b1y, uz = a2z - dot*b1z;
        float n2   = sqrtf(ux*ux + uy*uy + uz*uz);
        float inv2 = 1.0f / fmaxf(n2, 1e-12f);
        float b2x = ux*inv2, b2y = uy*inv2, b2z = uz*inv2;
        float b3x = b1y*b2z - b1z*b2y;
        float b3y = b1z*b2x - b1x*b2z;
        float b3z = b1x*b2y - b1y*b2x;

        float rt0 = b1x*xx + b1y*xy + b1z*xz;
        float rt1 = b2x*xx + b2y*xy + b2z*xz;
        float rt2 = b3x*xx + b3y*xy + b3z*xz;

        float at0 = b1x*rt0 + b2x*rt1;
        float at1 = b1y*rt0 + b2y*rt1;
        float at2 = b1z*rt0 + b2z*rt1;
        float bt0 = b2x*rt0 - b1x*rt1;
        float bt1 = b2y*rt0 - b1y*rt1;
        float bt2 = b2z*rt0 - b1z*rt1;
        float ct0 = b3x*rt2, ct1 = b3y*rt2, ct2 = b3z*rt2;

        bf16* r0 = &T_lds[(p*3 + 0) * TPITCH];
        bf16* r1 = &T_lds[(p*3 + 1) * TPITCH];
        bf16* r2 = &T_lds[(p*3 + 2) * TPITCH];
        r0[lane] = (bf16)at0; r0[64+lane] = (bf16)bt0; r0[128+lane] = (bf16)ct0;
        r1[lane] = (bf16)at1; r1[64+lane] = (bf16)bt1; r1[128+lane] = (bf16)ct1;
        r2[lane] = (bf16)at2; r2[64+lane] = (bf16)bt2; r2[128+lane] = (bf16)ct2;
    }
    __syncthreads();   // the ONLY block-wide barrier: T transpose complete

    // ---- MFMA: D[m, f] = sum_k T[m,k] * W[f,k] ----
    f32x4 acc[3];
    #pragma unroll
    for (int mt = 0; mt < 3; ++mt) {
        f32x4 a = {0.f, 0.f, 0.f, 0.f};
        const bf16* arow = &T_lds[(mt*16 + l16) * TPITCH + lq*8];
        #pragma unroll
        for (int kk = 0; kk < 6; ++kk) {
            bf16x8 af = *(const bf16x8*)(arow + kk*32);
            a = __builtin_amdgcn_mfma_f32_16x16x32_bf16(af, wfrag[kk], a, 0, 0, 0);
        }
        acc[mt] = a;
    }

    // ---- Wave-private Y scatter: this wave owns f in [16w, 16w+16) => per point a
    //      contiguous 48-float chunk. C/D layout: col=l16 (f_local), row=lq*4+r (m) ----
    float* yw = &Y_lds[wave][0];
    #pragma unroll
    for (int mt = 0; mt < 3; ++mt) {
        #pragma unroll
        for (int r = 0; r < 4; ++r) {
            int m = mt*16 + lq*4 + r;     // m = p*3 + i
            int p = m / 3, i = m - p*3;
            yw[p*48 + l16*3 + i] = acc[mt][r];
        }
    }
    // (compiler inserts lgkmcnt wait; same-wave RAW on LDS, no barrier needed)

    // ---- Wave-private writeout: 16 chunks of 192 B, 192 f32x4 total per wave ----
    const f32x4* ysrc = (const f32x4*)yw;
    #pragma unroll
    for (int v = 0; v < 3; ++v) {
        int vi = v * 64 + lane;           // 0..191
        int p  = vi / 12;                 // point within tile
        int vo = vi - p * 12;             // f32x4 index within 48-float chunk
        f32x4* dst = (f32x4*)(Y + (bn0 + p) * 192 + wave * 48) + vo;
        *dst = ysrc[vi];
    }
}

extern "C" void kernel_launch(void* const* d_in, const int* in_sizes, int n_in,
                              void* d_out, int out_size, void* d_ws, size_t ws_size,
                              hipStream_t stream) {
    const float* X  = (const float*)d_in[0];
    const float* J  = (const float*)d_in[1];
    const float* A  = (const float*)d_in[2];
    const float* Bm = (const float*)d_in[3];
    const float* C  = (const float*)d_in[4];
    float* Y = (float*)d_out;

    const int points = in_sizes[0] / (64 * 3);   // B*N = 65536
    const int blocks = points / PTS;             // 4096
    affine_linear_fused<<<blocks, 256, 0, stream>>>(X, J, A, Bm, C, Y);
}

// Round 4
// 203.540 us; speedup vs baseline: 1.0105x; 1.0105x over previous
//
#include <hip/hip_runtime.h>

typedef __bf16 bf16;
typedef bf16 bf16x8 __attribute__((ext_vector_type(8)));
typedef float f32x4 __attribute__((ext_vector_type(4)));
typedef unsigned int u32;

#define PTS 16          // points per block (4 per wave)
#define WREG 9216       // per-wave LDS region bytes
// Per-wave region layout (aliased phases):
//   phase 1 (stage):  [0,6144) J for 4 pts, [6144,9216) X for 4 pts
//   phase 2 (gemm):   [0,4800)  T = 12 rows x 400B pitch (m = wave*12 + q*3 + i)
//                     [4800,7872) Y staging, 16 pts x 48 floats (wave's 16 f-cols)
// Total LDS 4*9216 = 36864 B -> 4 blocks/CU (16 waves/CU), VGPR<=128.
// ONE __syncthreads (T transpose); J/X stage is wave-private (vmcnt-only).

__device__ __forceinline__ void gld_lds16(const void* g, void* l) {
    __builtin_amdgcn_global_load_lds(
        (const __attribute__((address_space(1))) u32*)g,
        (__attribute__((address_space(3))) u32*)l, 16, 0, 0);
}

__global__ __launch_bounds__(256, 4)
void affine_linear_fused(const float* __restrict__ X, const float* __restrict__ J,
                         const float* __restrict__ A, const float* __restrict__ Bm,
                         const float* __restrict__ C, float* __restrict__ Y)
{
    __shared__ __attribute__((aligned(128))) unsigned char lds[4 * WREG];

    const int tid  = threadIdx.x;
    const int wave = tid >> 6;
    const int lane = tid & 63;
    const int l16  = lane & 15;
    const int lq   = lane >> 4;       // quad 0..3
    const long bn0 = (long)blockIdx.x * PTS;

    unsigned char* wbase = &lds[wave * WREG];

    // ---- Phase 1: async coalesced stage of this wave's J (6144B) + X (3072B) ----
    {
        const float* jg = J + (bn0 + wave * 4) * 64 * 6;
        const float* xg = X + (bn0 + wave * 4) * 64 * 3;
        #pragma unroll
        for (int t = 0; t < 6; ++t)
            gld_lds16(jg + t * 256 + lane * 4, wbase + t * 1024);
        #pragma unroll
        for (int t = 0; t < 3; ++t)
            gld_lds16(xg + t * 256 + lane * 4, wbase + 6144 + t * 1024);
    }

    // ---- W fragments from global (L2/L3-hot after first blocks) ----
    // W[f,k]: f = wave*16+l16; k = kk*32 + lq*8 + j; kk<2:A, <4:Bm, else C
    const int f = wave * 16 + l16;
    bf16x8 wfrag[6];
    #pragma unroll
    for (int kk = 0; kk < 6; ++kk) {
        const float* src = (kk < 2) ? A : (kk < 4) ? Bm : C;
        const f32x4* p4 = (const f32x4*)(src + f * 64 + (kk & 1) * 32 + lq * 8);
        f32x4 lo = p4[0], hi = p4[1];
        bf16x8 w;
        w[0] = (bf16)lo[0]; w[1] = (bf16)lo[1]; w[2] = (bf16)lo[2]; w[3] = (bf16)lo[3];
        w[4] = (bf16)hi[0]; w[5] = (bf16)hi[1]; w[6] = (bf16)hi[2]; w[7] = (bf16)hi[3];
        wfrag[kk] = w;
    }

    // Wait for this wave's own staged J/X (also drains W loads; both needed now).
    __asm__ volatile("s_waitcnt vmcnt(0)" ::: "memory");

    // ---- Read all 4 points' J/X from LDS into registers, then compute ----
    const float* jlds = (const float*)wbase;            // [q*384 + d*6]
    const float* xlds = (const float*)(wbase + 6144);   // [q*192 + d*3]
    float jv[4][6], xv[4][3];
    #pragma unroll
    for (int q = 0; q < 4; ++q) {
        const float* jp = jlds + q * 384 + lane * 6;
        float2 ja = *(const float2*)(jp + 0);
        float2 jb = *(const float2*)(jp + 2);
        float2 jc = *(const float2*)(jp + 4);
        jv[q][0] = ja.x; jv[q][1] = ja.y;
        jv[q][2] = jb.x; jv[q][3] = jb.y;
        jv[q][4] = jc.x; jv[q][5] = jc.y;
        const float* xp = xlds + q * 192 + lane * 3;
        xv[q][0] = xp[0]; xv[q][1] = xp[1]; xv[q][2] = xp[2];
    }

    // ---- Terms; write T rows (aliases the now-dead J stage) ----
    #pragma unroll
    for (int q = 0; q < 4; ++q) {
        float a1x = jv[q][0], a2x = jv[q][1];
        float a1y = jv[q][2], a2y = jv[q][3];
        float a1z = jv[q][4], a2z = jv[q][5];
        float xx = xv[q][0], xy = xv[q][1], xz = xv[q][2];

        float n1   = sqrtf(a1x*a1x + a1y*a1y + a1z*a1z);
        float inv1 = 1.0f / fmaxf(n1, 1e-12f);
        float b1x = a1x*inv1, b1y = a1y*inv1, b1z = a1z*inv1;
        float dot = b1x*a2x + b1y*a2y + b1z*a2z;
        float ux = a2x - dot*b1x, uy = a2y - dot*b1y, uz = a2z - dot*b1z;
        float n2   = sqrtf(ux*ux + uy*uy + uz*uz);
        float inv2 = 1.0f / fmaxf(n2, 1e-12f);
        float b2x = ux*inv2, b2y = uy*inv2, b2z = uz*inv2;
        float b3x = b1y*b2z - b1z*b2y;
        float b3y = b1z*b2x - b1x*b2z;
        float b3z = b1x*b2y - b1y*b2x;

        float rt0 = b1x*xx + b1y*xy + b1z*xz;
        float rt1 = b2x*xx + b2y*xy + b2z*xz;
        float rt2 = b3x*xx + b3y*xy + b3z*xz;

        float at0 = b1x*rt0 + b2x*rt1;
        float at1 = b1y*rt0 + b2y*rt1;
        float at2 = b1z*rt0 + b2z*rt1;
        float bt0 = b2x*rt0 - b1x*rt1;
        float bt1 = b2y*rt0 - b1y*rt1;
        float bt2 = b2z*rt0 - b1z*rt1;
        float ct0 = b3x*rt2, ct1 = b3y*rt2, ct2 = b3z*rt2;

        bf16* r0 = (bf16*)(wbase + (q*3 + 0) * 400);
        bf16* r1 = (bf16*)(wbase + (q*3 + 1) * 400);
        bf16* r2 = (bf16*)(wbase + (q*3 + 2) * 400);
        r0[lane] = (bf16)at0; r0[64+lane] = (bf16)bt0; r0[128+lane] = (bf16)ct0;
        r1[lane] = (bf16)at1; r1[64+lane] = (bf16)bt1; r1[128+lane] = (bf16)ct1;
        r2[lane] = (bf16)at2; r2[64+lane] = (bf16)bt2; r2[128+lane] = (bf16)ct2;
    }
    __syncthreads();   // the ONLY block barrier: all T rows visible

    // ---- MFMA: D[m,f] = sum_k T[m,k] * W[f,k]; T row m = wave'*12 + r ----
    f32x4 acc[3];
    #pragma unroll
    for (int mt = 0; mt < 3; ++mt) {
        int m  = mt * 16 + l16;
        int wv = m / 12;
        int r  = m - wv * 12;
        const unsigned char* arow = &lds[wv * WREG + r * 400] + lq * 16;
        f32x4 a = {0.f, 0.f, 0.f, 0.f};
        #pragma unroll
        for (int kk = 0; kk < 6; ++kk) {
            bf16x8 af = *(const bf16x8*)(arow + kk * 64);
            a = __builtin_amdgcn_mfma_f32_16x16x32_bf16(af, wfrag[kk], a, 0, 0, 0);
        }
        acc[mt] = a;
    }

    // ---- Wave-private Y scatter: f-cols [16w,16w+16) => 48-float chunk per point ----
    float* yw = (float*)(wbase + 4800);
    #pragma unroll
    for (int mt = 0; mt < 3; ++mt) {
        #pragma unroll
        for (int r = 0; r < 4; ++r) {
            int m  = mt * 16 + lq * 4 + r;
            int wv = m / 12;
            int rr = m - wv * 12;
            int q  = rr / 3;
            int i  = rr - q * 3;
            int p  = wv * 4 + q;
            yw[p * 48 + l16 * 3 + i] = acc[mt][r];
        }
    }

    // ---- Wave-private coalesced writeout: 16 chunks of 192 B ----
    const f32x4* ysrc = (const f32x4*)yw;
    #pragma unroll
    for (int v = 0; v < 3; ++v) {
        int vi = v * 64 + lane;           // 0..191
        int p  = vi / 12;
        int vo = vi - p * 12;
        f32x4* dst = (f32x4*)(Y + (bn0 + p) * 192 + wave * 48) + vo;
        *dst = ysrc[vi];
    }
}

extern "C" void kernel_launch(void* const* d_in, const int* in_sizes, int n_in,
                              void* d_out, int out_size, void* d_ws, size_t ws_size,
                              hipStream_t stream) {
    const float* X  = (const float*)d_in[0];
    const float* J  = (const float*)d_in[1];
    const float* A  = (const float*)d_in[2];
    const float* Bm = (const float*)d_in[3];
    const float* C  = (const float*)d_in[4];
    float* Y = (float*)d_out;

    const int points = in_sizes[0] / (64 * 3);   // B*N = 65536
    const int blocks = points / PTS;             // 4096
    affine_linear_fused<<<blocks, 256, 0, stream>>>(X, J, A, Bm, C, Y);
}